// Round 5
// baseline (1252.285 us; speedup 1.0000x reference)
//
#include <hip/hip_runtime.h>
#include <stdint.h>

// Problem constants
#define B_SZ  8192
#define E_DIM 256
#define N_E   4096
#define N_L   3

// Output layout (float offsets): x_q[8192,256], loss[1], idx[8192,3],
// one_hot[8192,3,4096], logits[8192,3,4096]
#define XQ_OFF   0
#define LOSS_OFF 2097152
#define IDX_OFF  2097153
#define OH_OFF   2121729
#define LG_OFF   102785025

typedef unsigned long long u64;
typedef unsigned int u32;
typedef __attribute__((ext_vector_type(8))) __bf16 bf16x8;
typedef __attribute__((ext_vector_type(4))) float f32x4;

// Workspace layout (bytes):
//   keys1 u64[3][8192] @ 0          (196608)
//   keys2 u32[3][8192] @ 196608     (98304)   -> keys region [0,294912) one 0xFF memset
//   rn    f32[8192]    @ 294912
//   cn    f32[12288]   @ 327680
//   loss64 f32[64*16]  @ 376832     (4096, slots cacheline-spread)
//   Rhi   bf16[8192*256]  @ 524288
//   Chi   bf16[12288*256] @ 8912896
//   Clo                  @ 15204352  (end ~21.5 MB)
// (Rlo removed: 2-product split-bf16 — rl·ch term dropped, error 3e-5 << TAU)

__device__ __forceinline__ unsigned short f2bf_rne(float f) {
    u32 u = __float_as_uint(f);
    u += 0x7FFF + ((u >> 16) & 1);
    return (unsigned short)(u >> 16);
}
__device__ __forceinline__ float bf2f(unsigned short h) {
    return __uint_as_float((u32)h << 16);
}
__device__ __forceinline__ void gl_lds16(const void* g, void* l) {
    __builtin_amdgcn_global_load_lds((const __attribute__((address_space(1))) u32*)g,
                                     (__attribute__((address_space(3))) u32*)l, 16, 0, 0);
}

// ---------------------------------------------------------------- fused setup:
// blocks [0,2048): residual=x (4 rows/block, float4/lane), rn, bf16 hi split only
// blocks [2048,5120): codebook norms + bf16 hi/lo splits (4 rows/block)
__global__ __launch_bounds__(256) void setup(const float* __restrict__ x,
                                             float* __restrict__ resid,
                                             float* __restrict__ rn,
                                             unsigned short* __restrict__ Rhi,
                                             const float* __restrict__ cb,
                                             float* __restrict__ cn,
                                             unsigned short* __restrict__ Chi,
                                             unsigned short* __restrict__ Clo) {
    const int bid = blockIdx.x, t = threadIdx.x;
    const int lane = t & 63, wv = t >> 6;
    if (bid < B_SZ / 4) {
        const int b = bid * 4 + wv;
        const float4 v = ((const float4*)(x + (size_t)b * E_DIM))[lane];
        ((float4*)(resid + (size_t)b * E_DIM))[lane] = v;
        ushort4 h;
        h.x = f2bf_rne(v.x); h.y = f2bf_rne(v.y);
        h.z = f2bf_rne(v.z); h.w = f2bf_rne(v.w);
        ((ushort4*)(Rhi + (size_t)b * E_DIM))[lane] = h;
        float s = v.x * v.x + v.y * v.y + v.z * v.z + v.w * v.w;
#pragma unroll
        for (int o = 32; o; o >>= 1) s += __shfl_down(s, o);
        if (lane == 0) rn[b] = s;
    } else {
        const int row = (bid - B_SZ / 4) * 4 + wv;   // 0..12287
        const float4 v = ((const float4*)(cb + (size_t)row * E_DIM))[lane];
        ushort4 h, l;
        h.x = f2bf_rne(v.x); l.x = f2bf_rne(v.x - bf2f(h.x));
        h.y = f2bf_rne(v.y); l.y = f2bf_rne(v.y - bf2f(h.y));
        h.z = f2bf_rne(v.z); l.z = f2bf_rne(v.z - bf2f(h.z));
        h.w = f2bf_rne(v.w); l.w = f2bf_rne(v.w - bf2f(h.w));
        ((ushort4*)(Chi + (size_t)row * E_DIM))[lane] = h;
        ((ushort4*)(Clo + (size_t)row * E_DIM))[lane] = l;
        float s = v.x * v.x + v.y * v.y + v.z * v.z + v.w * v.w;
#pragma unroll
        for (int o = 32; o; o >>= 1) s += __shfl_down(s, o);
        if (lane == 0) cn[row] = s;
    }
}

// ---------------------------------------------------------------- MFMA split-bf16 distance GEMM
// 128x128 tile, BK=32, 256 thr = 4 waves, each wave 64x64 (4x4 16x16x32 tiles).
// 2 products (rh·ch + rh·cl; rl·ch dropped — err 3e-5 << TAU=2e-4, refine is exact fp32).
// 2-phase pipeline (dbuf LDS 48 KB -> 3 blocks/CU, STAGE(next) before compute, 1 barrier
// per K-step) + 16B-slot XOR swizzle (pre-swizzled global source, rule #21).
// logits/oh stores NONTEMPORAL (write-once stream, preserve L2 for staging).
#define GT_M 128
#define GT_N 128
#define GT_K 32
#define NSTEP (E_DIM / GT_K)

__global__ __launch_bounds__(256) void dist_gemm(
    const unsigned short* __restrict__ Ahi_g,
    const unsigned short* __restrict__ Bhi_g, const unsigned short* __restrict__ Blo_g,
    const float* __restrict__ rn, const float* __restrict__ cn,
    float* __restrict__ logits, float* __restrict__ oh,
    u64* __restrict__ keys1, u32* __restrict__ keys2, int layer) {
    __shared__ unsigned short Ah[2][GT_M * GT_K];
    __shared__ unsigned short Bh[2][GT_M * GT_K], Bl[2][GT_M * GT_K];   // 48 KB total
    const int tid = threadIdx.x;
    const int lane = tid & 63, w = tid >> 6;
    const int bm = blockIdx.y * GT_M, bn = blockIdx.x * GT_N;

    const unsigned short* A0 = Ahi_g + (size_t)bm * E_DIM;
    const unsigned short* B0 = Bhi_g + (size_t)bn * E_DIM;
    const unsigned short* B1 = Blo_g + (size_t)bn * E_DIM;

    // staging: chunk c = w*2+tt covers rows [c*16, c*16+16); lane ℓ: row c*16+(ℓ>>2),
    // physical 16B slot (ℓ&3). LDS dest linear (HW rule). Source piece pre-swizzled:
    // p = (ℓ&3) ^ s(row), s(row)=(row>>1)&3=(ℓ>>3)&3.
    const int srow_off = (lane >> 2);
    const size_t gsub = (size_t)(((lane & 3) ^ ((lane >> 3) & 3)) * 8);

#define STAGE(k0, buf)                                                              \
    {                                                                               \
        _Pragma("unroll")                                                           \
        for (int tt = 0; tt < 2; ++tt) {                                            \
            const int c = w * 2 + tt;                                               \
            const int row = c * 16 + srow_off;                                      \
            const size_t ge = (size_t)row * E_DIM + (k0) + gsub;                    \
            const int lo = (buf) * 8192 + c * 1024;                                 \
            gl_lds16(A0 + ge, (char*)Ah + lo);                                      \
            gl_lds16(B0 + ge, (char*)Bh + lo);                                      \
            gl_lds16(B1 + ge, (char*)Bl + lo);                                      \
        }                                                                           \
    }

    f32x4 acc[4][4] = {};

    const int wm = (w >> 1) * 64, wn = (w & 1) * 64;
    const int fr = lane & 15;          // fragment row (A/B m/n index)
    // read-side swizzled k offset: logical piece (lane>>4), s(row)=(fr>>1)&3=(lane>>1)&3
    const int fq = (((lane >> 4) ^ ((lane >> 1) & 3)) * 8);

    STAGE(0, 0);
    __syncthreads();
#pragma unroll
    for (int step = 0; step < NSTEP; ++step) {
        const int cur = step & 1;
        if (step + 1 < NSTEP) STAGE((step + 1) * GT_K, cur ^ 1);   // prefetch flies under MFMA
        bf16x8 ah[4], bh[4], bl[4];
#pragma unroll
        for (int mt = 0; mt < 4; ++mt)
            ah[mt] = *(const bf16x8*)&Ah[cur][(wm + mt * 16 + fr) * GT_K + fq];
#pragma unroll
        for (int nt = 0; nt < 4; ++nt) {
            bh[nt] = *(const bf16x8*)&Bh[cur][(wn + nt * 16 + fr) * GT_K + fq];
            bl[nt] = *(const bf16x8*)&Bl[cur][(wn + nt * 16 + fr) * GT_K + fq];
        }
#pragma unroll
        for (int mt = 0; mt < 4; ++mt)
#pragma unroll
            for (int nt = 0; nt < 4; ++nt) {
                acc[mt][nt] = __builtin_amdgcn_mfma_f32_16x16x32_bf16(ah[mt], bh[nt], acc[mt][nt], 0, 0, 0);
                acc[mt][nt] = __builtin_amdgcn_mfma_f32_16x16x32_bf16(ah[mt], bl[nt], acc[mt][nt], 0, 0, 0);
            }
        if (step + 1 < NSTEP) __syncthreads();   // drains vmcnt(0): next buf staged, cur buf free
    }

    // ---- epilogue: d = (rn+cn) - 2*acc ; write logits + oh zeros (nontemporal);
    //      global top-2 via atomics
    float cnv[4];
#pragma unroll
    for (int nt = 0; nt < 4; ++nt) cnv[nt] = cn[bn + wn + nt * 16 + fr];

#pragma unroll
    for (int mt = 0; mt < 4; ++mt) {
#pragma unroll
        for (int reg = 0; reg < 4; ++reg) {
            const int grow = bm + wm + mt * 16 + (lane >> 4) * 4 + reg;   // C/D row mapping (m89/m91)
            const float rv = rn[grow];
            float dv[4];
#pragma unroll
            for (int nt = 0; nt < 4; ++nt) {
                const float d = (rv + cnv[nt]) - 2.0f * acc[mt][nt][reg];
                const size_t off = ((size_t)grow * N_L + layer) * N_E + (size_t)(bn + wn + nt * 16 + fr);
                __builtin_nontemporal_store(d, &logits[off]);
                __builtin_nontemporal_store(0.0f, &oh[off]);
                dv[nt] = d;
            }
            // per-lane top-2 of 4 (ascending j: first-min tie-break)
            float d1 = dv[0], d2 = 1e30f;
            int j1 = bn + wn + fr;
#pragma unroll
            for (int nt = 1; nt < 4; ++nt) {
                const int jj = bn + wn + nt * 16 + fr;
                if (dv[nt] < d1) { d2 = d1; d1 = dv[nt]; j1 = jj; }
                else if (dv[nt] < d2) d2 = dv[nt];
            }
            u64 p1 = ((u64)__float_as_uint(d1) << 32) | (u32)j1;
            u32 d2b = __float_as_uint(d2);
#pragma unroll
            for (int o = 1; o <= 8; o <<= 1) {   // reduce across the 16 col-lanes
                const u64 op = __shfl_xor(p1, o);
                const u32 od = __shfl_xor(d2b, o);
                const u64 hi = p1 > op ? p1 : op;
                const u32 m2 = d2b < od ? d2b : od;
                const u32 hd = (u32)(hi >> 32);
                d2b = m2 < hd ? m2 : hd;
                p1 = p1 < op ? p1 : op;
            }
            if (fr == 0) {
                const u64 old = atomicMin(&keys1[grow], p1);
                const u64 loser = old > p1 ? old : p1;
                const u32 ld = (u32)(loser >> 32);
                atomicMin(&keys2[grow], d2b < ld ? d2b : ld);
            }
        }
    }
#undef STAGE
}

// ---------------------------------------------------------------- per-row update (+ near-tie refine)
// Refine: float4 logits scan + 4-wave-parallel candidate dots (float4/lane),
// winner via u64 (val_bits<<32 | j) min -> exact first-min tie-break (d always > 0).
// All __syncthreads remain block-uniform (trigger depends only on b).
// TAU=2e-4: covers the 2-product logits error (~3e-5; need 2*err < TAU).
#define TAU 2e-4f
__global__ __launch_bounds__(256) void vq_update(
    const float* __restrict__ C, const float* __restrict__ cn_l,
    const u64* __restrict__ keys1, const u32* __restrict__ keys2,
    const float* __restrict__ logits,
    float* __restrict__ resid, float* __restrict__ rn,
    unsigned short* __restrict__ Rhi,
    float* __restrict__ out_idx, float* __restrict__ oh,
    float* __restrict__ loss64, int layer) {
    const int b = blockIdx.x, t = threadIdx.x;
    __shared__ float red[4];
    __shared__ int s_cand[64];
    __shared__ int s_ncand;
    __shared__ u64 s_w[4];
    __shared__ int s_bestj;

    const u64 k1 = keys1[b];
    const float d1 = __uint_as_float((u32)(k1 >> 32));
    const float d2 = __uint_as_float(keys2[b]);
    int j = (int)(k1 & 0xFFFFFFFFull);

    if (d2 - d1 < TAU) {   // near-tie: re-decide with exact fp32 dots
        if (t == 0) s_ncand = 0;
        __syncthreads();
        const float4* lrow4 = (const float4*)(logits + ((size_t)b * N_L + layer) * N_E);
        const float lim = d1 + TAU;
#pragma unroll
        for (int g = 0; g < 4; ++g) {
            const int q4 = t + 256 * g;            // float4 index 0..1023
            const float4 v = lrow4[q4];
            if (v.x <= lim) { const int s = atomicAdd(&s_ncand, 1); if (s < 64) s_cand[s] = q4 * 4 + 0; }
            if (v.y <= lim) { const int s = atomicAdd(&s_ncand, 1); if (s < 64) s_cand[s] = q4 * 4 + 1; }
            if (v.z <= lim) { const int s = atomicAdd(&s_ncand, 1); if (s < 64) s_cand[s] = q4 * 4 + 2; }
            if (v.w <= lim) { const int s = atomicAdd(&s_ncand, 1); if (s < 64) s_cand[s] = q4 * 4 + 3; }
        }
        __syncthreads();
        const int nc = s_ncand < 64 ? s_ncand : 64;
        const int wv = t >> 6, lane = t & 63;
        const float4 rv4 = ((const float4*)(resid + (size_t)b * E_DIM))[lane];
        const float rnb = rn[b];
        u64 best = ~0ull;
        for (int ci = wv; ci < nc; ci += 4) {
            const int jj = s_cand[ci];
            const float4 c4 = ((const float4*)(C + (size_t)jj * E_DIM))[lane];
            float p = rv4.x * c4.x + rv4.y * c4.y + rv4.z * c4.z + rv4.w * c4.w;
#pragma unroll
            for (int o = 32; o; o >>= 1) p += __shfl_down(p, o);
            if (lane == 0) {
                const float val = (rnb + cn_l[jj]) - 2.0f * p;
                const u64 pk = ((u64)__float_as_uint(val) << 32) | (u32)jj;
                if (pk < best) best = pk;
            }
        }
        if ((t & 63) == 0) s_w[wv] = best;
        __syncthreads();
        if (t == 0) {
            u64 m = s_w[0];
            if (s_w[1] < m) m = s_w[1];
            if (s_w[2] < m) m = s_w[2];
            if (s_w[3] < m) m = s_w[3];
            s_bestj = (int)(m & 0xFFFFFFFFull);
        }
        __syncthreads();
        j = s_bestj;
    }

    const size_t ri = (size_t)b * E_DIM + t;
    const float qv = C[(size_t)j * E_DIM + t];
    const float r = resid[ri];
    const float nr = r - qv;               // new residual; loss term = nr^2
    resid[ri] = nr;
    Rhi[ri] = f2bf_rne(nr);
    float s = nr * nr;
#pragma unroll
    for (int o = 32; o; o >>= 1) s += __shfl_down(s, o);
    if ((t & 63) == 0) red[t >> 6] = s;
    __syncthreads();
    if (t == 0) {
        const float tot = red[0] + red[1] + red[2] + red[3];
        rn[b] = tot;                       // next layer's row norm
        atomicAdd(&loss64[(b & 63) << 4], tot);   // 64 cacheline-spread slots
        out_idx[b * N_L + layer] = (float)j;
        oh[((size_t)b * N_L + layer) * N_E + j] = 1.0f;
    }
}

// ---------------------------------------------------------------- x_q = x - residual, loss
__global__ __launch_bounds__(256) void finalize(const float* __restrict__ x,
                                                float* __restrict__ xq,
                                                const float* __restrict__ loss64,
                                                float* __restrict__ loss_out) {
    const int i = blockIdx.x * 256 + threadIdx.x;
    const float4 xv = ((const float4*)x)[i];
    const float4 rv = ((const float4*)xq)[i];
    float4 o;
    o.x = xv.x - rv.x; o.y = xv.y - rv.y; o.z = xv.z - rv.z; o.w = xv.w - rv.w;
    ((float4*)xq)[i] = o;
    if (blockIdx.x == 0 && threadIdx.x < 64) {
        float s = loss64[threadIdx.x << 4];
#pragma unroll
        for (int of = 32; of; of >>= 1) s += __shfl_down(s, of);
        if (threadIdx.x == 0) loss_out[0] = 1.25f * s / (3.0f * B_SZ * E_DIM);
    }
}

extern "C" void kernel_launch(void* const* d_in, const int* in_sizes, int n_in,
                              void* d_out, int out_size, void* d_ws, size_t ws_size,
                              hipStream_t stream) {
    (void)in_sizes; (void)n_in; (void)out_size; (void)ws_size;
    const float* x  = (const float*)d_in[0];
    const float* cb = (const float*)d_in[1];
    float* out = (float*)d_out;

    float* resid    = out + XQ_OFF;     // residual lives in x_q region until finalize
    float* loss_out = out + LOSS_OFF;
    float* idx_out  = out + IDX_OFF;
    float* oh       = out + OH_OFF;
    float* lg       = out + LG_OFF;

    char* ws = (char*)d_ws;
    u64* keys1 = (u64*)ws;                          // [3][8192]
    u32* keys2 = (u32*)(ws + 196608);               // [3][8192]
    float* rn  = (float*)(ws + 294912);
    float* cn  = (float*)(ws + 327680);
    float* loss64 = (float*)(ws + 376832);          // 64 slots x 16 floats
    unsigned short* Rhi = (unsigned short*)(ws + 524288);
    unsigned short* Chi = (unsigned short*)(ws + 8912896);
    unsigned short* Clo = (unsigned short*)(ws + 15204352);

    hipMemsetAsync(ws, 0xFF, 294912, stream);       // all 3 layers' keys at once
    hipMemsetAsync(loss64, 0, 4096, stream);
    setup<<<B_SZ / 4 + (N_L * N_E) / 4, 256, 0, stream>>>(x, resid, rn, Rhi,
                                                          cb, cn, Chi, Clo);

    for (int l = 0; l < N_L; ++l) {
        dim3 grid(N_E / GT_N, B_SZ / GT_M);
        dist_gemm<<<grid, 256, 0, stream>>>(Rhi,
                                            Chi + (size_t)l * N_E * E_DIM,
                                            Clo + (size_t)l * N_E * E_DIM,
                                            rn, cn + l * N_E, lg, oh,
                                            keys1 + l * B_SZ, keys2 + l * B_SZ, l);
        vq_update<<<B_SZ, 256, 0, stream>>>(cb + (size_t)l * N_E * E_DIM, cn + l * N_E,
                                            keys1 + l * B_SZ, keys2 + l * B_SZ, lg,
                                            resid, rn, Rhi,
                                            idx_out, oh, loss64, l);
    }
    finalize<<<B_SZ * E_DIM / 4 / 256, 256, 0, stream>>>(x, resid, loss64, loss_out);
}

// Round 7
// 1183.029 us; speedup vs baseline: 1.0585x; 1.0585x over previous
//
#include <hip/hip_runtime.h>
#include <stdint.h>

// Problem constants
#define B_SZ  8192
#define E_DIM 256
#define N_E   4096
#define N_L   3

// Output layout (float offsets): x_q[8192,256], loss[1], idx[8192,3],
// one_hot[8192,3,4096], logits[8192,3,4096]
#define XQ_OFF   0
#define LOSS_OFF 2097152
#define IDX_OFF  2097153
#define OH_OFF   2121729
#define LG_OFF   102785025

typedef unsigned long long u64;
typedef unsigned int u32;
typedef __attribute__((ext_vector_type(8))) __bf16 bf16x8;
typedef __attribute__((ext_vector_type(4))) float f32x4;

// Workspace layout (bytes):
//   keys1 u64[3][8192] @ 0          (196608)
//   keys2 u32[3][8192] @ 196608     (98304)   -> keys region [0,294912) one 0xFF memset
//   rn    f32[8192]    @ 294912
//   cn    f32[12288]   @ 327680
//   loss64 f32[64*16]  @ 376832     (4096, slots cacheline-spread)
//   Rhi   bf16[8192*256]  @ 524288
//   Rlo                  @ 4718592
//   Chi   bf16[12288*256] @ 8912896
//   Clo                  @ 15204352  (end ~21.5 MB)

__device__ __forceinline__ unsigned short f2bf_rne(float f) {
    u32 u = __float_as_uint(f);
    u += 0x7FFF + ((u >> 16) & 1);
    return (unsigned short)(u >> 16);
}
__device__ __forceinline__ float bf2f(unsigned short h) {
    return __uint_as_float((u32)h << 16);
}
__device__ __forceinline__ void gl_lds16(const void* g, void* l) {
    __builtin_amdgcn_global_load_lds((const __attribute__((address_space(1))) u32*)g,
                                     (__attribute__((address_space(3))) u32*)l, 16, 0, 0);
}

// ---------------------------------------------------------------- fused setup:
// blocks [0,2048): residual=x (4 rows/block, float4/lane), rn, bf16 splits
// blocks [2048,5120): codebook norms + bf16 splits (4 rows/block)
__global__ __launch_bounds__(256) void setup(const float* __restrict__ x,
                                             float* __restrict__ resid,
                                             float* __restrict__ rn,
                                             unsigned short* __restrict__ Rhi,
                                             unsigned short* __restrict__ Rlo,
                                             const float* __restrict__ cb,
                                             float* __restrict__ cn,
                                             unsigned short* __restrict__ Chi,
                                             unsigned short* __restrict__ Clo) {
    const int bid = blockIdx.x, t = threadIdx.x;
    const int lane = t & 63, wv = t >> 6;
    if (bid < B_SZ / 4) {
        const int b = bid * 4 + wv;
        const float4 v = ((const float4*)(x + (size_t)b * E_DIM))[lane];
        ((float4*)(resid + (size_t)b * E_DIM))[lane] = v;
        ushort4 h, l;
        h.x = f2bf_rne(v.x); l.x = f2bf_rne(v.x - bf2f(h.x));
        h.y = f2bf_rne(v.y); l.y = f2bf_rne(v.y - bf2f(h.y));
        h.z = f2bf_rne(v.z); l.z = f2bf_rne(v.z - bf2f(h.z));
        h.w = f2bf_rne(v.w); l.w = f2bf_rne(v.w - bf2f(h.w));
        ((ushort4*)(Rhi + (size_t)b * E_DIM))[lane] = h;
        ((ushort4*)(Rlo + (size_t)b * E_DIM))[lane] = l;
        float s = v.x * v.x + v.y * v.y + v.z * v.z + v.w * v.w;
#pragma unroll
        for (int o = 32; o; o >>= 1) s += __shfl_down(s, o);
        if (lane == 0) rn[b] = s;
    } else {
        const int row = (bid - B_SZ / 4) * 4 + wv;   // 0..12287
        const float4 v = ((const float4*)(cb + (size_t)row * E_DIM))[lane];
        ushort4 h, l;
        h.x = f2bf_rne(v.x); l.x = f2bf_rne(v.x - bf2f(h.x));
        h.y = f2bf_rne(v.y); l.y = f2bf_rne(v.y - bf2f(h.y));
        h.z = f2bf_rne(v.z); l.z = f2bf_rne(v.z - bf2f(h.z));
        h.w = f2bf_rne(v.w); l.w = f2bf_rne(v.w - bf2f(h.w));
        ((ushort4*)(Chi + (size_t)row * E_DIM))[lane] = h;
        ((ushort4*)(Clo + (size_t)row * E_DIM))[lane] = l;
        float s = v.x * v.x + v.y * v.y + v.z * v.z + v.w * v.w;
#pragma unroll
        for (int o = 32; o; o >>= 1) s += __shfl_down(s, o);
        if (lane == 0) cn[row] = s;
    }
}

// ---------------------------------------------------------------- MFMA split-bf16 distance GEMM
// 128x128 tile, BK=32, 256 thr = 4 waves, each wave 64x64 (4x4 16x16x32 tiles), 3 products.
// 2-phase pipeline (dbuf LDS 64 KB, STAGE(next) before compute, 1 barrier/K-step) + 16B-slot
// XOR swizzle (pre-swizzled global source, rule #21).
// Epilogue v3 (R5 diagnosis: epilogue-bound, not MFMA/staging-bound):
//   - oh zeros moved to one upfront 402 MB memset (fill kernel runs at 6.26 TB/s measured)
//   - logits stored as f32x4 via 16-lane shuffle transpose (4 shfl_xor rounds) ->
//     256 B contiguous runs, 16 store instrs/thread instead of 64+64 scattered 4 B.
#define GT_M 128
#define GT_N 128
#define GT_K 32
#define NSTEP (E_DIM / GT_K)

__global__ __launch_bounds__(256) void dist_gemm(
    const unsigned short* __restrict__ Ahi_g, const unsigned short* __restrict__ Alo_g,
    const unsigned short* __restrict__ Bhi_g, const unsigned short* __restrict__ Blo_g,
    const float* __restrict__ rn, const float* __restrict__ cn,
    float* __restrict__ logits,
    u64* __restrict__ keys1, u32* __restrict__ keys2, int layer) {
    __shared__ unsigned short Ah[2][GT_M * GT_K], Al[2][GT_M * GT_K];
    __shared__ unsigned short Bh[2][GT_M * GT_K], Bl[2][GT_M * GT_K];   // 64 KB total
    const int tid = threadIdx.x;
    const int lane = tid & 63, w = tid >> 6;
    const int bm = blockIdx.y * GT_M, bn = blockIdx.x * GT_N;

    const unsigned short* A0 = Ahi_g + (size_t)bm * E_DIM;
    const unsigned short* A1 = Alo_g + (size_t)bm * E_DIM;
    const unsigned short* B0 = Bhi_g + (size_t)bn * E_DIM;
    const unsigned short* B1 = Blo_g + (size_t)bn * E_DIM;

    // staging: chunk c = w*2+tt covers rows [c*16, c*16+16); lane ℓ: row c*16+(ℓ>>2),
    // physical 16B slot (ℓ&3). LDS dest linear (HW rule). Source piece pre-swizzled:
    // p = (ℓ&3) ^ s(row), s(row)=(row>>1)&3=(ℓ>>3)&3.
    const int srow_off = (lane >> 2);
    const size_t gsub = (size_t)(((lane & 3) ^ ((lane >> 3) & 3)) * 8);

#define STAGE(k0, buf)                                                              \
    {                                                                               \
        _Pragma("unroll")                                                           \
        for (int tt = 0; tt < 2; ++tt) {                                            \
            const int c = w * 2 + tt;                                               \
            const int row = c * 16 + srow_off;                                      \
            const size_t ge = (size_t)row * E_DIM + (k0) + gsub;                    \
            const int lo = (buf) * 8192 + c * 1024;                                 \
            gl_lds16(A0 + ge, (char*)Ah + lo);                                      \
            gl_lds16(A1 + ge, (char*)Al + lo);                                      \
            gl_lds16(B0 + ge, (char*)Bh + lo);                                      \
            gl_lds16(B1 + ge, (char*)Bl + lo);                                      \
        }                                                                           \
    }

    f32x4 acc[4][4] = {};

    const int wm = (w >> 1) * 64, wn = (w & 1) * 64;
    const int fr = lane & 15;          // fragment row (A/B m/n index)
    // read-side swizzled k offset: logical piece (lane>>4), s(row)=(fr>>1)&3=(lane>>1)&3
    const int fq = (((lane >> 4) ^ ((lane >> 1) & 3)) * 8);

    STAGE(0, 0);
    __syncthreads();
#pragma unroll
    for (int step = 0; step < NSTEP; ++step) {
        const int cur = step & 1;
        if (step + 1 < NSTEP) STAGE((step + 1) * GT_K, cur ^ 1);   // prefetch flies under MFMA
        bf16x8 ah[4], al[4], bh[4], bl[4];
#pragma unroll
        for (int mt = 0; mt < 4; ++mt) {
            ah[mt] = *(const bf16x8*)&Ah[cur][(wm + mt * 16 + fr) * GT_K + fq];
            al[mt] = *(const bf16x8*)&Al[cur][(wm + mt * 16 + fr) * GT_K + fq];
        }
#pragma unroll
        for (int nt = 0; nt < 4; ++nt) {
            bh[nt] = *(const bf16x8*)&Bh[cur][(wn + nt * 16 + fr) * GT_K + fq];
            bl[nt] = *(const bf16x8*)&Bl[cur][(wn + nt * 16 + fr) * GT_K + fq];
        }
#pragma unroll
        for (int mt = 0; mt < 4; ++mt)
#pragma unroll
            for (int nt = 0; nt < 4; ++nt) {
                acc[mt][nt] = __builtin_amdgcn_mfma_f32_16x16x32_bf16(ah[mt], bh[nt], acc[mt][nt], 0, 0, 0);
                acc[mt][nt] = __builtin_amdgcn_mfma_f32_16x16x32_bf16(ah[mt], bl[nt], acc[mt][nt], 0, 0, 0);
                acc[mt][nt] = __builtin_amdgcn_mfma_f32_16x16x32_bf16(al[mt], bh[nt], acc[mt][nt], 0, 0, 0);
            }
        if (step + 1 < NSTEP) __syncthreads();   // drains vmcnt(0): next buf staged, cur buf free
    }

    // ---- epilogue: d = (rn+cn) - 2*acc ; top-2 via atomics; coalesced f32x4 logits store
    float cnv[4];
#pragma unroll
    for (int nt = 0; nt < 4; ++nt) cnv[nt] = cn[bn + wn + nt * 16 + fr];

#pragma unroll
    for (int mt = 0; mt < 4; ++mt) {
#pragma unroll
        for (int reg = 0; reg < 4; ++reg) {
            const int grow = bm + wm + mt * 16 + (lane >> 4) * 4 + reg;   // C/D row mapping (m89/m91)
            const float rv = rn[grow];
            float dv[4];
#pragma unroll
            for (int nt = 0; nt < 4; ++nt)
                dv[nt] = (rv + cnv[nt]) - 2.0f * acc[mt][nt][reg];

            // per-lane top-2 of 4 (ascending j: first-min tie-break) on pre-transpose dv
            float d1 = dv[0], d2 = 1e30f;
            int j1 = bn + wn + fr;
#pragma unroll
            for (int nt = 1; nt < 4; ++nt) {
                const int jj = bn + wn + nt * 16 + fr;
                if (dv[nt] < d1) { d2 = d1; d1 = dv[nt]; j1 = jj; }
                else if (dv[nt] < d2) d2 = dv[nt];
            }
            u64 p1 = ((u64)__float_as_uint(d1) << 32) | (u32)j1;
            u32 d2b = __float_as_uint(d2);
#pragma unroll
            for (int o = 1; o <= 8; o <<= 1) {   // reduce across the 16 col-lanes
                const u64 op = __shfl_xor(p1, o);
                const u32 od = __shfl_xor(d2b, o);
                const u64 hi = p1 > op ? p1 : op;
                const u32 m2 = d2b < od ? d2b : od;
                const u32 hd = (u32)(hi >> 32);
                d2b = m2 < hd ? m2 : hd;
                p1 = p1 < op ? p1 : op;
            }
            if (fr == 0) {
                const u64 old = atomicMin(&keys1[grow], p1);
                const u64 loser = old > p1 ? old : p1;
                const u32 ld = (u32)(loser >> 32);
                atomicMin(&keys2[grow], d2b < ld ? d2b : ld);
            }

            // 16-lane shuffle transpose: lane (h=fr>>2, s=fr&3) reg j  <-  src lane (s,j) reg h.
            // After: lane fr holds cols [4*fr .. 4*fr+3] of its row -> one f32x4 store.
            // Rounds: high bits (mask 4 then 8), then low bits (mask 1 then 2). Verified
            // by trace: lane0 ends with [L0.v0, L1.v0, L2.v0, L3.v0] = cols 0..3 (nt=0).
            float v0 = dv[0], v1 = dv[1], v2 = dv[2], v3 = dv[3];
            {   // mask 4, reg pairs (0,1),(2,3)
                const bool hi2 = lane & 4;
                float a = hi2 ? v0 : v1, c = hi2 ? v2 : v3;
                a = __shfl_xor(a, 4); c = __shfl_xor(c, 4);
                if (hi2) { v0 = a; v2 = c; } else { v1 = a; v3 = c; }
            }
            {   // mask 8, reg pairs (0,2),(1,3)
                const bool hi2 = lane & 8;
                float a = hi2 ? v0 : v2, c = hi2 ? v1 : v3;
                a = __shfl_xor(a, 8); c = __shfl_xor(c, 8);
                if (hi2) { v0 = a; v1 = c; } else { v2 = a; v3 = c; }
            }
            {   // mask 1, reg pairs (0,1),(2,3)
                const bool hi2 = lane & 1;
                float a = hi2 ? v0 : v1, c = hi2 ? v2 : v3;
                a = __shfl_xor(a, 1); c = __shfl_xor(c, 1);
                if (hi2) { v0 = a; v2 = c; } else { v1 = a; v3 = c; }
            }
            {   // mask 2, reg pairs (0,2),(1,3)
                const bool hi2 = lane & 2;
                float a = hi2 ? v0 : v2, c = hi2 ? v1 : v3;
                a = __shfl_xor(a, 2); c = __shfl_xor(c, 2);
                if (hi2) { v0 = a; v1 = c; } else { v2 = a; v3 = c; }
            }
            const size_t off = ((size_t)grow * N_L + layer) * N_E + (size_t)(bn + wn + 4 * fr);
            f32x4 st;
            st.x = v0; st.y = v1; st.z = v2; st.w = v3;
            __builtin_nontemporal_store(st, (f32x4*)&logits[off]);
        }
    }
#undef STAGE
}

// ---------------------------------------------------------------- per-row update (+ near-tie refine)
// Refine: float4 logits scan + 4-wave-parallel candidate dots (float4/lane),
// winner via u64 (val_bits<<32 | j) min -> exact first-min tie-break (d always > 0).
// All __syncthreads remain block-uniform (trigger depends only on b).
#define TAU 1e-4f
__global__ __launch_bounds__(256) void vq_update(
    const float* __restrict__ C, const float* __restrict__ cn_l,
    const u64* __restrict__ keys1, const u32* __restrict__ keys2,
    const float* __restrict__ logits,
    float* __restrict__ resid, float* __restrict__ rn,
    unsigned short* __restrict__ Rhi, unsigned short* __restrict__ Rlo,
    float* __restrict__ out_idx, float* __restrict__ oh,
    float* __restrict__ loss64, int layer) {
    const int b = blockIdx.x, t = threadIdx.x;
    __shared__ float red[4];
    __shared__ int s_cand[64];
    __shared__ int s_ncand;
    __shared__ u64 s_w[4];
    __shared__ int s_bestj;

    const u64 k1 = keys1[b];
    const float d1 = __uint_as_float((u32)(k1 >> 32));
    const float d2 = __uint_as_float(keys2[b]);
    int j = (int)(k1 & 0xFFFFFFFFull);

    if (d2 - d1 < TAU) {   // near-tie: re-decide with exact fp32 dots
        if (t == 0) s_ncand = 0;
        __syncthreads();
        const float4* lrow4 = (const float4*)(logits + ((size_t)b * N_L + layer) * N_E);
        const float lim = d1 + TAU;
#pragma unroll
        for (int g = 0; g < 4; ++g) {
            const int q4 = t + 256 * g;            // float4 index 0..1023
            const float4 v = lrow4[q4];
            if (v.x <= lim) { const int s = atomicAdd(&s_ncand, 1); if (s < 64) s_cand[s] = q4 * 4 + 0; }
            if (v.y <= lim) { const int s = atomicAdd(&s_ncand, 1); if (s < 64) s_cand[s] = q4 * 4 + 1; }
            if (v.z <= lim) { const int s = atomicAdd(&s_ncand, 1); if (s < 64) s_cand[s] = q4 * 4 + 2; }
            if (v.w <= lim) { const int s = atomicAdd(&s_ncand, 1); if (s < 64) s_cand[s] = q4 * 4 + 3; }
        }
        __syncthreads();
        const int nc = s_ncand < 64 ? s_ncand : 64;
        const int wv = t >> 6, lane = t & 63;
        const float4 rv4 = ((const float4*)(resid + (size_t)b * E_DIM))[lane];
        const float rnb = rn[b];
        u64 best = ~0ull;
        for (int ci = wv; ci < nc; ci += 4) {
            const int jj = s_cand[ci];
            const float4 c4 = ((const float4*)(C + (size_t)jj * E_DIM))[lane];
            float p = rv4.x * c4.x + rv4.y * c4.y + rv4.z * c4.z + rv4.w * c4.w;
#pragma unroll
            for (int o = 32; o; o >>= 1) p += __shfl_down(p, o);
            if (lane == 0) {
                const float val = (rnb + cn_l[jj]) - 2.0f * p;
                const u64 pk = ((u64)__float_as_uint(val) << 32) | (u32)jj;
                if (pk < best) best = pk;
            }
        }
        if ((t & 63) == 0) s_w[wv] = best;
        __syncthreads();
        if (t == 0) {
            u64 m = s_w[0];
            if (s_w[1] < m) m = s_w[1];
            if (s_w[2] < m) m = s_w[2];
            if (s_w[3] < m) m = s_w[3];
            s_bestj = (int)(m & 0xFFFFFFFFull);
        }
        __syncthreads();
        j = s_bestj;
    }

    const size_t ri = (size_t)b * E_DIM + t;
    const float qv = C[(size_t)j * E_DIM + t];
    const float r = resid[ri];
    const float nr = r - qv;               // new residual; loss term = nr^2
    resid[ri] = nr;
    const unsigned short h = f2bf_rne(nr);
    Rhi[ri] = h;
    Rlo[ri] = f2bf_rne(nr - bf2f(h));
    float s = nr * nr;
#pragma unroll
    for (int o = 32; o; o >>= 1) s += __shfl_down(s, o);
    if ((t & 63) == 0) red[t >> 6] = s;
    __syncthreads();
    if (t == 0) {
        const float tot = red[0] + red[1] + red[2] + red[3];
        rn[b] = tot;                       // next layer's row norm
        atomicAdd(&loss64[(b & 63) << 4], tot);   // 64 cacheline-spread slots
        out_idx[b * N_L + layer] = (float)j;
        oh[((size_t)b * N_L + layer) * N_E + j] = 1.0f;
    }
}

// ---------------------------------------------------------------- x_q = x - residual, loss
__global__ __launch_bounds__(256) void finalize(const float* __restrict__ x,
                                                float* __restrict__ xq,
                                                const float* __restrict__ loss64,
                                                float* __restrict__ loss_out) {
    const int i = blockIdx.x * 256 + threadIdx.x;
    const float4 xv = ((const float4*)x)[i];
    const float4 rv = ((const float4*)xq)[i];
    float4 o;
    o.x = xv.x - rv.x; o.y = xv.y - rv.y; o.z = xv.z - rv.z; o.w = xv.w - rv.w;
    ((float4*)xq)[i] = o;
    if (blockIdx.x == 0 && threadIdx.x < 64) {
        float s = loss64[threadIdx.x << 4];
#pragma unroll
        for (int of = 32; of; of >>= 1) s += __shfl_down(s, of);
        if (threadIdx.x == 0) loss_out[0] = 1.25f * s / (3.0f * B_SZ * E_DIM);
    }
}

extern "C" void kernel_launch(void* const* d_in, const int* in_sizes, int n_in,
                              void* d_out, int out_size, void* d_ws, size_t ws_size,
                              hipStream_t stream) {
    (void)in_sizes; (void)n_in; (void)out_size; (void)ws_size;
    const float* x  = (const float*)d_in[0];
    const float* cb = (const float*)d_in[1];
    float* out = (float*)d_out;

    float* resid    = out + XQ_OFF;     // residual lives in x_q region until finalize
    float* loss_out = out + LOSS_OFF;
    float* idx_out  = out + IDX_OFF;
    float* oh       = out + OH_OFF;
    float* lg       = out + LG_OFF;

    char* ws = (char*)d_ws;
    u64* keys1 = (u64*)ws;                          // [3][8192]
    u32* keys2 = (u32*)(ws + 196608);               // [3][8192]
    float* rn  = (float*)(ws + 294912);
    float* cn  = (float*)(ws + 327680);
    float* loss64 = (float*)(ws + 376832);          // 64 slots x 16 floats
    unsigned short* Rhi = (unsigned short*)(ws + 524288);
    unsigned short* Rlo = (unsigned short*)(ws + 4718592);
    unsigned short* Chi = (unsigned short*)(ws + 8912896);
    unsigned short* Clo = (unsigned short*)(ws + 15204352);

    (void)hipMemsetAsync(ws, 0xFF, 294912, stream);       // all 3 layers' keys at once
    (void)hipMemsetAsync(loss64, 0, 4096, stream);
    // one_hot zeros for ALL layers in one optimal fill (dist_gemm no longer writes oh;
    // vq_update writes the single 1.0 per (b,layer) afterward in stream order)
    (void)hipMemsetAsync(oh, 0, (size_t)B_SZ * N_L * N_E * sizeof(float), stream);
    setup<<<B_SZ / 4 + (N_L * N_E) / 4, 256, 0, stream>>>(x, resid, rn, Rhi, Rlo,
                                                          cb, cn, Chi, Clo);

    for (int l = 0; l < N_L; ++l) {
        dim3 grid(N_E / GT_N, B_SZ / GT_M);
        dist_gemm<<<grid, 256, 0, stream>>>(Rhi, Rlo,
                                            Chi + (size_t)l * N_E * E_DIM,
                                            Clo + (size_t)l * N_E * E_DIM,
                                            rn, cn + l * N_E, lg,
                                            keys1 + l * B_SZ, keys2 + l * B_SZ, l);
        vq_update<<<B_SZ, 256, 0, stream>>>(cb + (size_t)l * N_E * E_DIM, cn + l * N_E,
                                            keys1 + l * B_SZ, keys2 + l * B_SZ, lg,
                                            resid, rn, Rhi, Rlo,
                                            idx_out, oh, loss64, l);
    }
    finalize<<<B_SZ * E_DIM / 4 / 256, 256, 0, stream>>>(x, resid, loss64, loss_out);
}

// Round 8
// 1132.441 us; speedup vs baseline: 1.1058x; 1.0447x over previous
//
#include <hip/hip_runtime.h>
#include <stdint.h>

// Problem constants
#define B_SZ  8192
#define E_DIM 256
#define N_E   4096
#define N_L   3

// Output layout (float offsets): x_q[8192,256], loss[1], idx[8192,3],
// one_hot[8192,3,4096], logits[8192,3,4096]
#define XQ_OFF   0
#define LOSS_OFF 2097152
#define IDX_OFF  2097153
#define OH_OFF   2121729
#define LG_OFF   102785025

typedef unsigned long long u64;
typedef unsigned int u32;
typedef __attribute__((ext_vector_type(8))) __bf16 bf16x8;
typedef __attribute__((ext_vector_type(4))) float f32x4;

// Workspace layout (bytes):
//   candA u64[3][8192][64] @ 0         (12582912)  per-(row, bn-slot) top-1 pack (d1<<32|j)
//   candB u32[3][8192][64] @ 12582912  (6291456)   per-(row, bn-slot) runner-up d2 bits
//     -> every slot written unconditionally by dist_gemm; NO init memset needed
//   rn    f32[8192]    @ 18874368
//   cn    f32[12288]   @ 18907136
//   loss64 f32[64*16]  @ 18956288     (4096, slots cacheline-spread)
//   Rhi   bf16[8192*256]  @ 18960384
//   Rlo                  @ 23154688
//   Chi   bf16[12288*256] @ 27348992
//   Clo                  @ 33640448   (end ~40 MB)

__device__ __forceinline__ unsigned short f2bf_rne(float f) {
    u32 u = __float_as_uint(f);
    u += 0x7FFF + ((u >> 16) & 1);
    return (unsigned short)(u >> 16);
}
__device__ __forceinline__ float bf2f(unsigned short h) {
    return __uint_as_float((u32)h << 16);
}
__device__ __forceinline__ void gl_lds16(const void* g, void* l) {
    __builtin_amdgcn_global_load_lds((const __attribute__((address_space(1))) u32*)g,
                                     (__attribute__((address_space(3))) u32*)l, 16, 0, 0);
}

// ---------------------------------------------------------------- fused setup:
// blocks [0,2048): residual=x (4 rows/block, float4/lane), rn, bf16 splits
// blocks [2048,5120): codebook norms + bf16 splits (4 rows/block)
__global__ __launch_bounds__(256) void setup(const float* __restrict__ x,
                                             float* __restrict__ resid,
                                             float* __restrict__ rn,
                                             unsigned short* __restrict__ Rhi,
                                             unsigned short* __restrict__ Rlo,
                                             const float* __restrict__ cb,
                                             float* __restrict__ cn,
                                             unsigned short* __restrict__ Chi,
                                             unsigned short* __restrict__ Clo) {
    const int bid = blockIdx.x, t = threadIdx.x;
    const int lane = t & 63, wv = t >> 6;
    if (bid < B_SZ / 4) {
        const int b = bid * 4 + wv;
        const float4 v = ((const float4*)(x + (size_t)b * E_DIM))[lane];
        ((float4*)(resid + (size_t)b * E_DIM))[lane] = v;
        ushort4 h, l;
        h.x = f2bf_rne(v.x); l.x = f2bf_rne(v.x - bf2f(h.x));
        h.y = f2bf_rne(v.y); l.y = f2bf_rne(v.y - bf2f(h.y));
        h.z = f2bf_rne(v.z); l.z = f2bf_rne(v.z - bf2f(h.z));
        h.w = f2bf_rne(v.w); l.w = f2bf_rne(v.w - bf2f(h.w));
        ((ushort4*)(Rhi + (size_t)b * E_DIM))[lane] = h;
        ((ushort4*)(Rlo + (size_t)b * E_DIM))[lane] = l;
        float s = v.x * v.x + v.y * v.y + v.z * v.z + v.w * v.w;
#pragma unroll
        for (int o = 32; o; o >>= 1) s += __shfl_down(s, o);
        if (lane == 0) rn[b] = s;
    } else {
        const int row = (bid - B_SZ / 4) * 4 + wv;   // 0..12287
        const float4 v = ((const float4*)(cb + (size_t)row * E_DIM))[lane];
        ushort4 h, l;
        h.x = f2bf_rne(v.x); l.x = f2bf_rne(v.x - bf2f(h.x));
        h.y = f2bf_rne(v.y); l.y = f2bf_rne(v.y - bf2f(h.y));
        h.z = f2bf_rne(v.z); l.z = f2bf_rne(v.z - bf2f(h.z));
        h.w = f2bf_rne(v.w); l.w = f2bf_rne(v.w - bf2f(h.w));
        ((ushort4*)(Chi + (size_t)row * E_DIM))[lane] = h;
        ((ushort4*)(Clo + (size_t)row * E_DIM))[lane] = l;
        float s = v.x * v.x + v.y * v.y + v.z * v.z + v.w * v.w;
#pragma unroll
        for (int o = 32; o; o >>= 1) s += __shfl_down(s, o);
        if (lane == 0) cn[row] = s;
    }
}

// ---------------------------------------------------------------- MFMA split-bf16 distance GEMM
// 128x128 tile, BK=32, 256 thr = 4 waves, each wave 64x64 (4x4 16x16x32 tiles), 3 products.
// 2-phase pipeline (dbuf LDS 64 KB, STAGE(next) before compute, 1 barrier/K-step) + 16B-slot
// XOR swizzle (pre-swizzled global source, rule #21).
// Epilogue v4 (R7 diagnosis: atomic-tail-bound):
//   - oh zeros via upfront memset (R7); logits via 16-lane shuffle transpose -> f32x4 NT
//   - NO ATOMICS: per-row top-2 written non-atomically to cand[grow][slot]
//     (slot = blockIdx.x*2 + wn-half, 64 slots/row); vq_update shuffle-reduces them.
#define GT_M 128
#define GT_N 128
#define GT_K 32
#define NSTEP (E_DIM / GT_K)

__global__ __launch_bounds__(256) void dist_gemm(
    const unsigned short* __restrict__ Ahi_g, const unsigned short* __restrict__ Alo_g,
    const unsigned short* __restrict__ Bhi_g, const unsigned short* __restrict__ Blo_g,
    const float* __restrict__ rn, const float* __restrict__ cn,
    float* __restrict__ logits,
    u64* __restrict__ candA, u32* __restrict__ candB, int layer) {
    __shared__ unsigned short Ah[2][GT_M * GT_K], Al[2][GT_M * GT_K];
    __shared__ unsigned short Bh[2][GT_M * GT_K], Bl[2][GT_M * GT_K];   // 64 KB total
    const int tid = threadIdx.x;
    const int lane = tid & 63, w = tid >> 6;
    const int bm = blockIdx.y * GT_M, bn = blockIdx.x * GT_N;

    const unsigned short* A0 = Ahi_g + (size_t)bm * E_DIM;
    const unsigned short* A1 = Alo_g + (size_t)bm * E_DIM;
    const unsigned short* B0 = Bhi_g + (size_t)bn * E_DIM;
    const unsigned short* B1 = Blo_g + (size_t)bn * E_DIM;

    // staging: chunk c = w*2+tt covers rows [c*16, c*16+16); lane ℓ: row c*16+(ℓ>>2),
    // physical 16B slot (ℓ&3). LDS dest linear (HW rule). Source piece pre-swizzled:
    // p = (ℓ&3) ^ s(row), s(row)=(row>>1)&3=(ℓ>>3)&3.
    const int srow_off = (lane >> 2);
    const size_t gsub = (size_t)(((lane & 3) ^ ((lane >> 3) & 3)) * 8);

#define STAGE(k0, buf)                                                              \
    {                                                                               \
        _Pragma("unroll")                                                           \
        for (int tt = 0; tt < 2; ++tt) {                                            \
            const int c = w * 2 + tt;                                               \
            const int row = c * 16 + srow_off;                                      \
            const size_t ge = (size_t)row * E_DIM + (k0) + gsub;                    \
            const int lo = (buf) * 8192 + c * 1024;                                 \
            gl_lds16(A0 + ge, (char*)Ah + lo);                                      \
            gl_lds16(A1 + ge, (char*)Al + lo);                                      \
            gl_lds16(B0 + ge, (char*)Bh + lo);                                      \
            gl_lds16(B1 + ge, (char*)Bl + lo);                                      \
        }                                                                           \
    }

    f32x4 acc[4][4] = {};

    const int wm = (w >> 1) * 64, wn = (w & 1) * 64;
    const int fr = lane & 15;          // fragment row (A/B m/n index)
    // read-side swizzled k offset: logical piece (lane>>4), s(row)=(fr>>1)&3=(lane>>1)&3
    const int fq = (((lane >> 4) ^ ((lane >> 1) & 3)) * 8);

    STAGE(0, 0);
    __syncthreads();
#pragma unroll
    for (int step = 0; step < NSTEP; ++step) {
        const int cur = step & 1;
        if (step + 1 < NSTEP) STAGE((step + 1) * GT_K, cur ^ 1);   // prefetch flies under MFMA
        bf16x8 ah[4], al[4], bh[4], bl[4];
#pragma unroll
        for (int mt = 0; mt < 4; ++mt) {
            ah[mt] = *(const bf16x8*)&Ah[cur][(wm + mt * 16 + fr) * GT_K + fq];
            al[mt] = *(const bf16x8*)&Al[cur][(wm + mt * 16 + fr) * GT_K + fq];
        }
#pragma unroll
        for (int nt = 0; nt < 4; ++nt) {
            bh[nt] = *(const bf16x8*)&Bh[cur][(wn + nt * 16 + fr) * GT_K + fq];
            bl[nt] = *(const bf16x8*)&Bl[cur][(wn + nt * 16 + fr) * GT_K + fq];
        }
#pragma unroll
        for (int mt = 0; mt < 4; ++mt)
#pragma unroll
            for (int nt = 0; nt < 4; ++nt) {
                acc[mt][nt] = __builtin_amdgcn_mfma_f32_16x16x32_bf16(ah[mt], bh[nt], acc[mt][nt], 0, 0, 0);
                acc[mt][nt] = __builtin_amdgcn_mfma_f32_16x16x32_bf16(ah[mt], bl[nt], acc[mt][nt], 0, 0, 0);
                acc[mt][nt] = __builtin_amdgcn_mfma_f32_16x16x32_bf16(al[mt], bh[nt], acc[mt][nt], 0, 0, 0);
            }
        if (step + 1 < NSTEP) __syncthreads();   // drains vmcnt(0): next buf staged, cur buf free
    }

    // ---- epilogue: d = (rn+cn) - 2*acc ; per-block top-2 -> cand slots; f32x4 logits
    float cnv[4];
#pragma unroll
    for (int nt = 0; nt < 4; ++nt) cnv[nt] = cn[bn + wn + nt * 16 + fr];

    const int slot = blockIdx.x * 2 + (w & 1);   // 64 slots per row

#pragma unroll
    for (int mt = 0; mt < 4; ++mt) {
#pragma unroll
        for (int reg = 0; reg < 4; ++reg) {
            const int grow = bm + wm + mt * 16 + (lane >> 4) * 4 + reg;   // C/D row mapping (m89/m91)
            const float rv = rn[grow];
            float dv[4];
#pragma unroll
            for (int nt = 0; nt < 4; ++nt)
                dv[nt] = (rv + cnv[nt]) - 2.0f * acc[mt][nt][reg];

            // per-lane top-2 of 4 (ascending j: first-min tie-break) on pre-transpose dv
            float d1 = dv[0], d2 = 1e30f;
            int j1 = bn + wn + fr;
#pragma unroll
            for (int nt = 1; nt < 4; ++nt) {
                const int jj = bn + wn + nt * 16 + fr;
                if (dv[nt] < d1) { d2 = d1; d1 = dv[nt]; j1 = jj; }
                else if (dv[nt] < d2) d2 = dv[nt];
            }
            u64 p1 = ((u64)__float_as_uint(d1) << 32) | (u32)j1;
            u32 d2b = __float_as_uint(d2);
#pragma unroll
            for (int o = 1; o <= 8; o <<= 1) {   // reduce across the 16 col-lanes
                const u64 op = __shfl_xor(p1, o);
                const u32 od = __shfl_xor(d2b, o);
                const u64 hi = p1 > op ? p1 : op;
                const u32 m2 = d2b < od ? d2b : od;
                const u32 hd = (u32)(hi >> 32);
                d2b = m2 < hd ? m2 : hd;
                p1 = p1 < op ? p1 : op;
            }
            if (fr == 0) {   // plain stores, no atomics (each (grow,slot) written once)
                candA[(size_t)grow * 64 + slot] = p1;
                candB[(size_t)grow * 64 + slot] = d2b;
            }

            // 16-lane shuffle transpose: lane (h=fr>>2, s=fr&3) reg j  <-  src lane (s,j) reg h.
            // After: lane fr holds cols [4*fr .. 4*fr+3] of its row -> one f32x4 store.
            float v0 = dv[0], v1 = dv[1], v2 = dv[2], v3 = dv[3];
            {   // mask 4, reg pairs (0,1),(2,3)
                const bool hi2 = lane & 4;
                float a = hi2 ? v0 : v1, c = hi2 ? v2 : v3;
                a = __shfl_xor(a, 4); c = __shfl_xor(c, 4);
                if (hi2) { v0 = a; v2 = c; } else { v1 = a; v3 = c; }
            }
            {   // mask 8, reg pairs (0,2),(1,3)
                const bool hi2 = lane & 8;
                float a = hi2 ? v0 : v2, c = hi2 ? v1 : v3;
                a = __shfl_xor(a, 8); c = __shfl_xor(c, 8);
                if (hi2) { v0 = a; v1 = c; } else { v2 = a; v3 = c; }
            }
            {   // mask 1, reg pairs (0,1),(2,3)
                const bool hi2 = lane & 1;
                float a = hi2 ? v0 : v1, c = hi2 ? v2 : v3;
                a = __shfl_xor(a, 1); c = __shfl_xor(c, 1);
                if (hi2) { v0 = a; v2 = c; } else { v1 = a; v3 = c; }
            }
            {   // mask 2, reg pairs (0,2),(1,3)
                const bool hi2 = lane & 2;
                float a = hi2 ? v0 : v2, c = hi2 ? v1 : v3;
                a = __shfl_xor(a, 2); c = __shfl_xor(c, 2);
                if (hi2) { v0 = a; v1 = c; } else { v2 = a; v3 = c; }
            }
            const size_t off = ((size_t)grow * N_L + layer) * N_E + (size_t)(bn + wn + 4 * fr);
            f32x4 st;
            st.x = v0; st.y = v1; st.z = v2; st.w = v3;
            __builtin_nontemporal_store(st, (f32x4*)&logits[off]);
        }
    }
#undef STAGE
}

// ---------------------------------------------------------------- per-row update (+ near-tie refine)
// Top-2 via 64-lane shuffle reduce over the 64 cand slots (same associative merge as the
// old atomic path -> identical selection semantics). Refine unchanged (exact fp32 dots).
#define TAU 1e-4f
__global__ __launch_bounds__(256) void vq_update(
    const float* __restrict__ C, const float* __restrict__ cn_l,
    const u64* __restrict__ candA, const u32* __restrict__ candB,
    const float* __restrict__ logits,
    float* __restrict__ resid, float* __restrict__ rn,
    unsigned short* __restrict__ Rhi, unsigned short* __restrict__ Rlo,
    float* __restrict__ out_idx, float* __restrict__ oh,
    float* __restrict__ loss64, int layer) {
    const int b = blockIdx.x, t = threadIdx.x;
    __shared__ float red[4];
    __shared__ int s_cand[64];
    __shared__ int s_ncand;
    __shared__ u64 s_w[4];
    __shared__ int s_bestj;
    __shared__ u64 s_key;
    __shared__ u32 s_d2;

    if (t < 64) {   // wave 0: reduce 64 candidate pairs
        u64 p1 = candA[(size_t)b * 64 + t];
        u32 d2b = candB[(size_t)b * 64 + t];
#pragma unroll
        for (int o = 1; o <= 32; o <<= 1) {
            const u64 op = __shfl_xor(p1, o);
            const u32 od = __shfl_xor(d2b, o);
            const u64 hi = p1 > op ? p1 : op;
            const u32 m2 = d2b < od ? d2b : od;
            const u32 hd = (u32)(hi >> 32);
            d2b = m2 < hd ? m2 : hd;
            p1 = p1 < op ? p1 : op;
        }
        if (t == 0) { s_key = p1; s_d2 = d2b; }
    }
    __syncthreads();

    const float d1 = __uint_as_float((u32)(s_key >> 32));
    const float d2 = __uint_as_float(s_d2);
    int j = (int)(s_key & 0xFFFFFFFFull);

    if (d2 - d1 < TAU) {   // near-tie: re-decide with exact fp32 dots
        if (t == 0) s_ncand = 0;
        __syncthreads();
        const float4* lrow4 = (const float4*)(logits + ((size_t)b * N_L + layer) * N_E);
        const float lim = d1 + TAU;
#pragma unroll
        for (int g = 0; g < 4; ++g) {
            const int q4 = t + 256 * g;            // float4 index 0..1023
            const float4 v = lrow4[q4];
            if (v.x <= lim) { const int s = atomicAdd(&s_ncand, 1); if (s < 64) s_cand[s] = q4 * 4 + 0; }
            if (v.y <= lim) { const int s = atomicAdd(&s_ncand, 1); if (s < 64) s_cand[s] = q4 * 4 + 1; }
            if (v.z <= lim) { const int s = atomicAdd(&s_ncand, 1); if (s < 64) s_cand[s] = q4 * 4 + 2; }
            if (v.w <= lim) { const int s = atomicAdd(&s_ncand, 1); if (s < 64) s_cand[s] = q4 * 4 + 3; }
        }
        __syncthreads();
        const int nc = s_ncand < 64 ? s_ncand : 64;
        const int wv = t >> 6, lane = t & 63;
        const float4 rv4 = ((const float4*)(resid + (size_t)b * E_DIM))[lane];
        const float rnb = rn[b];
        u64 best = ~0ull;
        for (int ci = wv; ci < nc; ci += 4) {
            const int jj = s_cand[ci];
            const float4 c4 = ((const float4*)(C + (size_t)jj * E_DIM))[lane];
            float p = rv4.x * c4.x + rv4.y * c4.y + rv4.z * c4.z + rv4.w * c4.w;
#pragma unroll
            for (int o = 32; o; o >>= 1) p += __shfl_down(p, o);
            if (lane == 0) {
                const float val = (rnb + cn_l[jj]) - 2.0f * p;
                const u64 pk = ((u64)__float_as_uint(val) << 32) | (u32)jj;
                if (pk < best) best = pk;
            }
        }
        if ((t & 63) == 0) s_w[wv] = best;
        __syncthreads();
        if (t == 0) {
            u64 m = s_w[0];
            if (s_w[1] < m) m = s_w[1];
            if (s_w[2] < m) m = s_w[2];
            if (s_w[3] < m) m = s_w[3];
            s_bestj = (int)(m & 0xFFFFFFFFull);
        }
        __syncthreads();
        j = s_bestj;
    }

    const size_t ri = (size_t)b * E_DIM + t;
    const float qv = C[(size_t)j * E_DIM + t];
    const float r = resid[ri];
    const float nr = r - qv;               // new residual; loss term = nr^2
    resid[ri] = nr;
    const unsigned short h = f2bf_rne(nr);
    Rhi[ri] = h;
    Rlo[ri] = f2bf_rne(nr - bf2f(h));
    float s = nr * nr;
#pragma unroll
    for (int o = 32; o; o >>= 1) s += __shfl_down(s, o);
    if ((t & 63) == 0) red[t >> 6] = s;
    __syncthreads();
    if (t == 0) {
        const float tot = red[0] + red[1] + red[2] + red[3];
        rn[b] = tot;                       // next layer's row norm
        atomicAdd(&loss64[(b & 63) << 4], tot);   // 64 cacheline-spread slots
        out_idx[b * N_L + layer] = (float)j;
        oh[((size_t)b * N_L + layer) * N_E + j] = 1.0f;
    }
}

// ---------------------------------------------------------------- x_q = x - residual, loss
__global__ __launch_bounds__(256) void finalize(const float* __restrict__ x,
                                                float* __restrict__ xq,
                                                const float* __restrict__ loss64,
                                                float* __restrict__ loss_out) {
    const int i = blockIdx.x * 256 + threadIdx.x;
    const float4 xv = ((const float4*)x)[i];
    const float4 rv = ((const float4*)xq)[i];
    float4 o;
    o.x = xv.x - rv.x; o.y = xv.y - rv.y; o.z = xv.z - rv.z; o.w = xv.w - rv.w;
    ((float4*)xq)[i] = o;
    if (blockIdx.x == 0 && threadIdx.x < 64) {
        float s = loss64[threadIdx.x << 4];
#pragma unroll
        for (int of = 32; of; of >>= 1) s += __shfl_down(s, of);
        if (threadIdx.x == 0) loss_out[0] = 1.25f * s / (3.0f * B_SZ * E_DIM);
    }
}

extern "C" void kernel_launch(void* const* d_in, const int* in_sizes, int n_in,
                              void* d_out, int out_size, void* d_ws, size_t ws_size,
                              hipStream_t stream) {
    (void)in_sizes; (void)n_in; (void)out_size; (void)ws_size;
    const float* x  = (const float*)d_in[0];
    const float* cb = (const float*)d_in[1];
    float* out = (float*)d_out;

    float* resid    = out + XQ_OFF;     // residual lives in x_q region until finalize
    float* loss_out = out + LOSS_OFF;
    float* idx_out  = out + IDX_OFF;
    float* oh       = out + OH_OFF;
    float* lg       = out + LG_OFF;

    char* ws = (char*)d_ws;
    u64* candA = (u64*)ws;                          // [3][8192][64]
    u32* candB = (u32*)(ws + 12582912);             // [3][8192][64]
    float* rn  = (float*)(ws + 18874368);
    float* cn  = (float*)(ws + 18907136);
    float* loss64 = (float*)(ws + 18956288);        // 64 slots x 16 floats
    unsigned short* Rhi = (unsigned short*)(ws + 18960384);
    unsigned short* Rlo = (unsigned short*)(ws + 23154688);
    unsigned short* Chi = (unsigned short*)(ws + 27348992);
    unsigned short* Clo = (unsigned short*)(ws + 33640448);

    (void)hipMemsetAsync(loss64, 0, 4096, stream);
    // one_hot zeros for ALL layers in one optimal fill (dist_gemm doesn't write oh;
    // vq_update writes the single 1.0 per (b,layer) afterward in stream order)
    (void)hipMemsetAsync(oh, 0, (size_t)B_SZ * N_L * N_E * sizeof(float), stream);
    setup<<<B_SZ / 4 + (N_L * N_E) / 4, 256, 0, stream>>>(x, resid, rn, Rhi, Rlo,
                                                          cb, cn, Chi, Clo);

    for (int l = 0; l < N_L; ++l) {
        dim3 grid(N_E / GT_N, B_SZ / GT_M);
        dist_gemm<<<grid, 256, 0, stream>>>(Rhi, Rlo,
                                            Chi + (size_t)l * N_E * E_DIM,
                                            Clo + (size_t)l * N_E * E_DIM,
                                            rn, cn + l * N_E, lg,
                                            candA + (size_t)l * B_SZ * 64,
                                            candB + (size_t)l * B_SZ * 64, l);
        vq_update<<<B_SZ, 256, 0, stream>>>(cb + (size_t)l * N_E * E_DIM, cn + l * N_E,
                                            candA + (size_t)l * B_SZ * 64,
                                            candB + (size_t)l * B_SZ * 64, lg,
                                            resid, rn, Rhi, Rlo,
                                            idx_out, oh, loss64, l);
    }
    finalize<<<B_SZ * E_DIM / 4 / 256, 256, 0, stream>>>(x, resid, loss64, loss_out);
}